// Round 8
// baseline (660.320 us; speedup 1.0000x reference)
//
#include <hip/hip_runtime.h>
#include <hip/hip_bf16.h>
#include <math.h>

#define N    50000
#define E    800000
#define NCT  32
#define EMB  256
#define HID  128
#define OUTD 512
#define NB_SCAN 49   // ceil(N/1024)

__device__ __forceinline__ float4 fma4s(float a, float4 b, float4 c) {
    return make_float4(fmaf(a, b.x, c.x), fmaf(a, b.y, c.y),
                       fmaf(a, b.z, c.z), fmaf(a, b.w, c.w));
}
__device__ __forceinline__ float4 add4(float4 a, float4 b) {
    return make_float4(a.x + b.x, a.y + b.y, a.z + b.z, a.w + b.w);
}

// ---------------------------------------------------------------------------
// k_init: ct = argmax(onehot), hist = 0, softplus(dispersion) transposed
// ---------------------------------------------------------------------------
__global__ void k_init(const float* __restrict__ onehot,
                       const float* __restrict__ dispersion,
                       int* __restrict__ ct, int* __restrict__ hist,
                       float* __restrict__ spt) {
    int i = blockIdx.x * 256 + threadIdx.x;
    if (i < N) {
        const float* row = onehot + (size_t)i * NCT;
        int c = 0;
        #pragma unroll
        for (int j = 0; j < NCT; j++)
            if (row[j] > 0.5f) c = j;
        ct[i] = c;
        hist[i] = 0;
    }
    if (i < OUTD * NCT) {
        float x = dispersion[i];                 // [OUTD][NCT], i = c*32 + j
        float s = log1pf(expf(-fabsf(x))) + fmaxf(x, 0.f);
        int c = i >> 5, j = i & 31;
        spt[j * OUTD + c] = s;                   // transposed [NCT][OUTD]
    }
}

// ---------------------------------------------------------------------------
// k_embed: x[n] = elu(We[ct_n] + lds_n*We[32] + be), materialized ONCE.
// 64 consecutive lanes share one node -> ct/lds broadcast; float4 I/O.
// ---------------------------------------------------------------------------
__global__ __launch_bounds__(256) void k_embed(
        const int* __restrict__ ct, const float* __restrict__ ldsc,
        const float* __restrict__ We, const float* __restrict__ be,
        float* __restrict__ x) {
    int gid = blockIdx.x * 256 + threadIdx.x;    // one float4 per thread
    if (gid >= N * (EMB / 4)) return;
    int n  = gid >> 6;
    int d  = (gid & 63) * 4;
    int c  = ct[n];
    float l = ldsc[n];
    float4 wc  = *reinterpret_cast<const float4*>(We + (size_t)c * EMB + d);
    float4 w32 = *reinterpret_cast<const float4*>(We + (size_t)NCT * EMB + d);
    float4 bb  = *reinterpret_cast<const float4*>(be + d);
    float4 v;
    v.x = fmaf(l, w32.x, wc.x) + bb.x;
    v.y = fmaf(l, w32.y, wc.y) + bb.y;
    v.z = fmaf(l, w32.z, wc.z) + bb.z;
    v.w = fmaf(l, w32.w, wc.w) + bb.w;
    v.x = v.x > 0.f ? v.x : expm1f(v.x);
    v.y = v.y > 0.f ? v.y : expm1f(v.y);
    v.z = v.z > 0.f ? v.z : expm1f(v.z);
    v.w = v.w > 0.f ? v.w : expm1f(v.w);
    *reinterpret_cast<float4*>(x + (size_t)n * EMB + d) = v;
}

// ---------------------------------------------------------------------------
// k_hist: histogram of dst (int4 vectorized)
// ---------------------------------------------------------------------------
__global__ __launch_bounds__(256) void k_hist(const int* __restrict__ eidx,
                                              int* __restrict__ hist) {
    int i = blockIdx.x * 256 + threadIdx.x;
    if (i < E / 4) {
        int4 d = reinterpret_cast<const int4*>(eidx + E)[i];
        atomicAdd(&hist[d.x], 1);
        atomicAdd(&hist[d.y], 1);
        atomicAdd(&hist[d.z], 1);
        atomicAdd(&hist[d.w], 1);
    }
}

// ---------------------------------------------------------------------------
// k_xlr v3: pure GEMM x[64-tile] @ (Wl or Wr, by blockIdx&1).
// A read from global (32 lanes/rowgrp share addr -> L1 broadcast, x is L2-hot).
// B double-buffered in LDS (2 x 16 KB, one barrier per 32-k chunk).
// 256 thr = 8 rowgrp x 32 colgrp; thread = 8 rows x 4 cols.
// ---------------------------------------------------------------------------
__global__ __launch_bounds__(256, 4) void k_xlr(
        const float* __restrict__ x,
        const float* __restrict__ pWl, const float* __restrict__ pbl,
        const float* __restrict__ pWr, const float* __restrict__ pbr,
        float* __restrict__ xl, float* __restrict__ xr) {
    __shared__ float Bs[2][32 * HID];            // 2 x 16 KB
    const int t  = threadIdx.x;
    const int b  = blockIdx.x & 1;               // 0: Wl->xl, 1: Wr->xr
    const int n0 = (blockIdx.x >> 1) * 64;
    const float* Wp = b ? pWr : pWl;

    const int rg = t >> 5;                       // rows rg*8..+7
    const int cg = t & 31;
    const int c  = cg * 4;
    const int row0 = n0 + rg * 8;
    // clamped row pointers (tail tile)
    const float* xrow[8];
    #pragma unroll
    for (int r = 0; r < 8; r++) {
        int n = row0 + r; if (n >= N) n = N - 1;
        xrow[r] = x + (size_t)n * EMB;
    }
    // staging map: fi = t + j*256; kk = t>>5 + j*8, col = (t&31)*4
    const int st_kk  = t >> 5;
    const int st_col = (t & 31) * 4;

    float4 acc[8];
    #pragma unroll
    for (int r = 0; r < 8; r++) acc[r] = make_float4(0.f, 0.f, 0.f, 0.f);

    // stage chunk 0
    #pragma unroll
    for (int j = 0; j < 4; j++) {
        int kk = st_kk + j * 8;
        *reinterpret_cast<float4*>(&Bs[0][kk * HID + st_col]) =
            *reinterpret_cast<const float4*>(Wp + (size_t)kk * HID + st_col);
    }
    __syncthreads();

    for (int kc = 0; kc < EMB; kc += 32) {
        const int cur = (kc >> 5) & 1;
        if (kc + 32 < EMB) {
            #pragma unroll
            for (int j = 0; j < 4; j++) {
                int kk = st_kk + j * 8;
                *reinterpret_cast<float4*>(&Bs[cur ^ 1][kk * HID + st_col]) =
                    *reinterpret_cast<const float4*>(Wp + (size_t)(kc + 32 + kk) * HID + st_col);
            }
        }
        #pragma unroll
        for (int kk = 0; kk < 32; kk += 4) {
            float4 bq[4];
            #pragma unroll
            for (int q = 0; q < 4; q++)
                bq[q] = *reinterpret_cast<const float4*>(&Bs[cur][(kk + q) * HID + c]);
            float4 a[8];
            #pragma unroll
            for (int r = 0; r < 8; r++)
                a[r] = *reinterpret_cast<const float4*>(xrow[r] + kc + kk);
            #pragma unroll
            for (int r = 0; r < 8; r++) {
                acc[r] = fma4s(a[r].x, bq[0], acc[r]);
                acc[r] = fma4s(a[r].y, bq[1], acc[r]);
                acc[r] = fma4s(a[r].z, bq[2], acc[r]);
                acc[r] = fma4s(a[r].w, bq[3], acc[r]);
            }
        }
        __syncthreads();
    }

    float* outP = b ? xr : xl;
    const float4 bias = *reinterpret_cast<const float4*>((b ? pbr : pbl) + c);
    #pragma unroll
    for (int r = 0; r < 8; r++) {
        int n = row0 + r;
        if (n < N)
            *reinterpret_cast<float4*>(outP + (size_t)n * HID + c) = add4(acc[r], bias);
    }
}

// ---------------------------------------------------------------------------
// 3-phase exclusive scan of hist[N] -> offs[N+1], cursor copy
// ---------------------------------------------------------------------------
__global__ __launch_bounds__(1024) void k_scan1(const int* __restrict__ hist,
                                                int* __restrict__ offs,
                                                int* __restrict__ bsum) {
    __shared__ int sb[2][1024];
    const int t = threadIdx.x;
    const int i = blockIdx.x * 1024 + t;
    int v = (i < N) ? hist[i] : 0;
    sb[0][t] = v;
    __syncthreads();
    int pin = 0;
    for (int off = 1; off < 1024; off <<= 1) {
        int x = sb[pin][t];
        if (t >= off) x += sb[pin][t - off];
        sb[pin ^ 1][t] = x;
        pin ^= 1;
        __syncthreads();
    }
    int incl = sb[pin][t];
    if (i < N) offs[i] = incl - v;
    if (t == 1023) bsum[blockIdx.x] = incl;
}

__global__ void k_scan2(const int* __restrict__ bsum, int* __restrict__ bbase) {
    if (threadIdx.x == 0) {
        int run = 0;
        for (int j = 0; j < NB_SCAN; j++) { bbase[j] = run; run += bsum[j]; }
    }
}

__global__ __launch_bounds__(1024) void k_scan3(int* __restrict__ offs,
                                                int* __restrict__ cursor,
                                                const int* __restrict__ bbase) {
    const int t = threadIdx.x;
    const int i = blockIdx.x * 1024 + t;
    if (i < N) {
        int v = offs[i] + bbase[blockIdx.x];
        offs[i] = v;
        cursor[i] = v;
    }
    if (blockIdx.x == 0 && t == 0) offs[N] = E;
}

// ---------------------------------------------------------------------------
// k_scatter: CSR adjacency storing SRC node id per slot (grouped by dst)
// ---------------------------------------------------------------------------
__global__ __launch_bounds__(256) void k_scatter(const int* __restrict__ eidx,
                                                 int* __restrict__ cursor,
                                                 int* __restrict__ sorted) {
    const int e = blockIdx.x * 256 + threadIdx.x;
    if (e < E) {
        int s = eidx[e];
        int d = eidx[E + e];
        int pos = atomicAdd(&cursor[d], 1);
        sorted[pos] = s;
    }
}

// ---------------------------------------------------------------------------
// k_agg: fused edge-logit + online scatter-softmax + aggregation.
// 32 lanes per node (float4/lane), 2 nodes per wave, branchless online
// update, 4-deep row prefetch. Writes h over xr (own row only).
// ---------------------------------------------------------------------------
__global__ __launch_bounds__(256, 8) void k_agg(
        const int* __restrict__ offs, const int* __restrict__ srt,
        const float* __restrict__ xl, const float* __restrict__ attv,
        const float* __restrict__ gb, float* xrh) {
    const int t = threadIdx.x;
    const int n = blockIdx.x * 8 + (t >> 5);
    if (n >= N) return;
    const int lane = t & 31;
    const float4* xl4 = reinterpret_cast<const float4*>(xl);
    float4* xh4 = reinterpret_cast<float4*>(xrh);

    const float4 xr4 = xh4[(size_t)n * 32 + lane];
    const float4 at4 = reinterpret_cast<const float4*>(attv)[lane];
    const int i0  = offs[n];
    const int deg = offs[n + 1] - i0;

    float m = -3.0e38f, den = 0.f;
    float4 acc = make_float4(0.f, 0.f, 0.f, 0.f);

#define STEP(XC) {                                                          \
    float vx = XC.x + xr4.x, vy = XC.y + xr4.y,                             \
          vz = XC.z + xr4.z, vw = XC.w + xr4.w;                             \
    vx = fmaxf(vx, 0.f) + 0.2f * fminf(vx, 0.f);                            \
    vy = fmaxf(vy, 0.f) + 0.2f * fminf(vy, 0.f);                            \
    vz = fmaxf(vz, 0.f) + 0.2f * fminf(vz, 0.f);                            \
    vw = fmaxf(vw, 0.f) + 0.2f * fminf(vw, 0.f);                            \
    float p = fmaf(vx, at4.x, fmaf(vy, at4.y, fmaf(vz, at4.z, vw * at4.w)));\
    p += __shfl_xor(p, 16); p += __shfl_xor(p, 8);                          \
    p += __shfl_xor(p, 4);  p += __shfl_xor(p, 2); p += __shfl_xor(p, 1);   \
    float mn = fmaxf(m, p);                                                 \
    float sc = __expf(m - mn);                                              \
    float w  = __expf(p - mn);                                              \
    den   = fmaf(den, sc, w);                                               \
    acc.x = fmaf(acc.x, sc, w * XC.x);                                      \
    acc.y = fmaf(acc.y, sc, w * XC.y);                                      \
    acc.z = fmaf(acc.z, sc, w * XC.z);                                      \
    acc.w = fmaf(acc.w, sc, w * XC.w);                                      \
    m = mn; }

    if (deg > 0) {
        const int lastI = i0 + deg - 1;
        #define LDX(J) xl4[(size_t)srt[min(i0 + (J), lastI)] * 32 + lane]
        float4 x0 = LDX(0), x1 = LDX(1), x2 = LDX(2), x3 = LDX(3);
        int i = 0;
        for (; i + 4 <= deg; i += 4) {
            const int base = i0 + i + 4;
            float4 n0 = xl4[(size_t)srt[min(base + 0, lastI)] * 32 + lane];
            float4 n1 = xl4[(size_t)srt[min(base + 1, lastI)] * 32 + lane];
            float4 n2 = xl4[(size_t)srt[min(base + 2, lastI)] * 32 + lane];
            float4 n3 = xl4[(size_t)srt[min(base + 3, lastI)] * 32 + lane];
            STEP(x0); STEP(x1); STEP(x2); STEP(x3);
            x0 = n0; x1 = n1; x2 = n2; x3 = n3;
        }
        if (i     < deg) STEP(x0);
        if (i + 1 < deg) STEP(x1);
        if (i + 2 < deg) STEP(x2);
        #undef LDX
    }
#undef STEP

    float inv = 1.f / (den + 1e-16f);
    const float4 g4 = reinterpret_cast<const float4*>(gb)[lane];
    float hx = fmaf(acc.x, inv, g4.x);
    float hy = fmaf(acc.y, inv, g4.y);
    float hz = fmaf(acc.z, inv, g4.z);
    float hw = fmaf(acc.w, inv, g4.w);
    hx = hx > 0.f ? hx : expm1f(hx);
    hy = hy > 0.f ? hy : expm1f(hy);
    hz = hz > 0.f ? hz : expm1f(hz);
    hw = hw > 0.f ? hw : expm1f(hw);
    xh4[(size_t)n * 32 + lane] = make_float4(hx, hy, hz, hw);
}

// ---------------------------------------------------------------------------
// k_out v2: block = 32 rows x 512 cols; 256 thr = 4 rowgrp(=wave: perfect
// A broadcast) x 64 colgrp; thread = 8 rows x 8 cols (two col-halves).
// ---------------------------------------------------------------------------
__global__ __launch_bounds__(256, 3) void k_out(
        const float* __restrict__ h, const int* __restrict__ ct,
        const float* __restrict__ Wo, const float* __restrict__ bo,
        const float* __restrict__ spt, float* __restrict__ out) {
    __shared__ float hs[32 * HID];   // 16 KB
    __shared__ float Bs[16 * OUTD];  // 32 KB
    __shared__ int ctl[32];
    const int t  = threadIdx.x;
    const int n0 = blockIdx.x * 32;

    if (t < 32) { int n = n0 + t; ctl[t] = ct[n < N ? n : N - 1]; }
    {
        const float4* h4 = reinterpret_cast<const float4*>(h);
        #pragma unroll
        for (int j = 0; j < 4; j++) {
            int fi  = t + j * 256;           // 0..1023
            int row = fi >> 5;               // 0..31
            int k4  = (fi & 31) * 4;
            int n = n0 + row;
            float4 v = (n < N) ? h4[(size_t)n * 32 + (fi & 31)]
                               : make_float4(0.f, 0.f, 0.f, 0.f);
            *reinterpret_cast<float4*>(&hs[row * HID + k4]) = v;
        }
    }

    const int rg = t >> 6;                   // wave id: rows rg*8..+7
    const int cg = t & 63;
    const int c0 = cg * 4;                   // col-half 0
    const int c1 = 256 + cg * 4;             // col-half 1
    const float* hrow = hs + rg * 8 * HID;
    const int st_kk  = t >> 7;
    const int st_col = (t & 127) * 4;

    float4 acc0[8], acc1[8];
    #pragma unroll
    for (int r = 0; r < 8; r++) {
        acc0[r] = make_float4(0.f, 0.f, 0.f, 0.f);
        acc1[r] = make_float4(0.f, 0.f, 0.f, 0.f);
    }

    for (int kc = 0; kc < HID; kc += 16) {
        __syncthreads();                     // hs ready / prev chunk consumed
        #pragma unroll
        for (int j = 0; j < 8; j++) {
            int kk = st_kk + j * 2;
            *reinterpret_cast<float4*>(&Bs[kk * OUTD + st_col]) =
                *reinterpret_cast<const float4*>(Wo + (size_t)(kc + kk) * OUTD + st_col);
        }
        __syncthreads();

        #pragma unroll
        for (int kk = 0; kk < 16; kk += 4) {
            float4 a[8];
            #pragma unroll
            for (int r = 0; r < 8; r++)
                a[r] = *reinterpret_cast<const float4*>(hrow + r * HID + kc + kk);
            #pragma unroll
            for (int q = 0; q < 4; q++) {
                float4 b0 = *reinterpret_cast<const float4*>(&Bs[(kk + q) * OUTD + c0]);
                float4 b1 = *reinterpret_cast<const float4*>(&Bs[(kk + q) * OUTD + c1]);
                const float* aq = reinterpret_cast<const float*>(a);
                #pragma unroll
                for (int r = 0; r < 8; r++) {
                    float av = aq[r * 4 + q];
                    acc0[r] = fma4s(av, b0, acc0[r]);
                    acc1[r] = fma4s(av, b1, acc1[r]);
                }
            }
        }
    }

    float* outd = out + (size_t)N * OUTD;
    const float4 bias0 = *reinterpret_cast<const float4*>(bo + c0);
    const float4 bias1 = *reinterpret_cast<const float4*>(bo + c1);
    #pragma unroll
    for (int r = 0; r < 8; r++) {
        int row = rg * 8 + r;
        int n = n0 + row;
        if (n < N) {
            *reinterpret_cast<float4*>(out + (size_t)n * OUTD + c0) = add4(acc0[r], bias0);
            *reinterpret_cast<float4*>(out + (size_t)n * OUTD + c1) = add4(acc1[r], bias1);
            int cn = ctl[row];
            *reinterpret_cast<float4*>(outd + (size_t)n * OUTD + c0) =
                *reinterpret_cast<const float4*>(spt + cn * OUTD + c0);
            *reinterpret_cast<float4*>(outd + (size_t)n * OUTD + c1) =
                *reinterpret_cast<const float4*>(spt + cn * OUTD + c1);
        }
    }
}

// ---------------------------------------------------------------------------
extern "C" void kernel_launch(void* const* d_in, const int* in_sizes, int n_in,
                              void* d_out, int out_size, void* d_ws, size_t ws_size,
                              hipStream_t stream) {
    const float* onehot     = (const float*)d_in[0];
    const float* ldsc       = (const float*)d_in[1];
    const int*   eidx       = (const int*)  d_in[2];
    const float* We         = (const float*)d_in[3];
    const float* be         = (const float*)d_in[4];
    const float* Wl         = (const float*)d_in[5];
    const float* bl         = (const float*)d_in[6];
    const float* Wr         = (const float*)d_in[7];
    const float* br         = (const float*)d_in[8];
    const float* attv       = (const float*)d_in[9];
    const float* gb         = (const float*)d_in[10];
    const float* Wo         = (const float*)d_in[11];
    const float* bo         = (const float*)d_in[12];
    const float* dispersion = (const float*)d_in[13];

    float* ws     = (float*)d_ws;
    float* xl     = ws;                               // N*HID
    float* xr     = xl + (size_t)N * HID;             // N*HID (h after k_agg)
    int*   sorted = (int*)(xr + (size_t)N * HID);     // E (src ids by dst)
    int*   ct     = sorted + E;                       // N
    int*   offs   = ct + N;                           // N+1
    int*   cursor = offs + (N + 1);                   // N+1
    int*   hist   = cursor + (N + 1);                 // N
    float* spt    = (float*)(hist + N);               // NCT*OUTD
    int*   bsum   = (int*)(spt + NCT * OUTD);         // 64
    int*   bbase  = bsum + 64;                        // 64
    float* x      = (float*)(bbase + 64);             // N*EMB (materialized embed)

    float* out = (float*)d_out;

    const int xlr_tiles = (N + 63) / 64;              // 782

    k_init   <<<(N + 255) / 256, 256, 0, stream>>>(onehot, dispersion, ct, hist, spt);
    k_embed  <<<(N * (EMB / 4) + 255) / 256, 256, 0, stream>>>(ct, ldsc, We, be, x);
    k_hist   <<<(E / 4 + 255) / 256, 256, 0, stream>>>(eidx, hist);
    k_xlr    <<<xlr_tiles * 2, 256, 0, stream>>>(x, Wl, bl, Wr, br, xl, xr);
    k_scan1  <<<NB_SCAN, 1024, 0, stream>>>(hist, offs, bsum);
    k_scan2  <<<1, 64, 0, stream>>>(bsum, bbase);
    k_scan3  <<<NB_SCAN, 1024, 0, stream>>>(offs, cursor, bbase);
    k_scatter<<<(E + 255) / 256, 256, 0, stream>>>(eidx, cursor, sorted);
    k_agg    <<<(N + 7) / 8, 256, 0, stream>>>(offs, sorted, xl, attv, gb, xr);
    k_out    <<<(N + 31) / 32, 256, 0, stream>>>(xr, ct, Wo, bo, spt, out);
}

// Round 9
// 565.639 us; speedup vs baseline: 1.1674x; 1.1674x over previous
//
#include <hip/hip_runtime.h>
#include <hip/hip_bf16.h>
#include <math.h>

#define N    50000
#define E    800000
#define NCT  32
#define EMB  256
#define HID  128
#define OUTD 512
#define NB_SCAN 49   // ceil(N/1024)

__device__ __forceinline__ float4 fma4s(float a, float4 b, float4 c) {
    return make_float4(fmaf(a, b.x, c.x), fmaf(a, b.y, c.y),
                       fmaf(a, b.z, c.z), fmaf(a, b.w, c.w));
}
__device__ __forceinline__ float4 add4(float4 a, float4 b) {
    return make_float4(a.x + b.x, a.y + b.y, a.z + b.z, a.w + b.w);
}

// ---------------------------------------------------------------------------
// k_init: ct = argmax(onehot), hist = 0, softplus(dispersion) transposed
// ---------------------------------------------------------------------------
__global__ void k_init(const float* __restrict__ onehot,
                       const float* __restrict__ dispersion,
                       int* __restrict__ ct, int* __restrict__ hist,
                       float* __restrict__ spt) {
    int i = blockIdx.x * 256 + threadIdx.x;
    if (i < N) {
        const float* row = onehot + (size_t)i * NCT;
        int c = 0;
        #pragma unroll
        for (int j = 0; j < NCT; j++)
            if (row[j] > 0.5f) c = j;
        ct[i] = c;
        hist[i] = 0;
    }
    if (i < OUTD * NCT) {
        float x = dispersion[i];                 // [OUTD][NCT], i = c*32 + j
        float s = log1pf(expf(-fabsf(x))) + fmaxf(x, 0.f);
        int c = i >> 5, j = i & 31;
        spt[j * OUTD + c] = s;                   // transposed [NCT][OUTD]
    }
}

// ---------------------------------------------------------------------------
// k_hist: histogram of dst (int4 vectorized)
// ---------------------------------------------------------------------------
__global__ __launch_bounds__(256) void k_hist(const int* __restrict__ eidx,
                                              int* __restrict__ hist) {
    int i = blockIdx.x * 256 + threadIdx.x;
    if (i < E / 4) {
        int4 d = reinterpret_cast<const int4*>(eidx + E)[i];
        atomicAdd(&hist[d.x], 1);
        atomicAdd(&hist[d.y], 1);
        atomicAdd(&hist[d.z], 1);
        atomicAdd(&hist[d.w], 1);
    }
}

// ---------------------------------------------------------------------------
// k_xlr v5: fused embed+ELU+GEMM. 32-row x 256-combined-col tile
// ([Wl | Wr] -> [xl | xr]); embed computed ONCE per row, cooperatively.
// 256 thr: rowgrp = t>>6 (wave-uniform -> A reads are pure LDS broadcast),
// colgrp = t&63; thread = 8 rows x 4 cols; 1 ds_read_b128 of B per 64
// FMA-cycles. Bs double-buffered, one barrier per 16-k chunk.
// LDS = 32 (xs) + 32 (Bs) = 64 KB -> 2 blocks/CU.
// ---------------------------------------------------------------------------
__global__ __launch_bounds__(256, 4) void k_xlr(
        const int* __restrict__ ct, const float* __restrict__ ldsc,
        const float* __restrict__ We, const float* __restrict__ be,
        const float* __restrict__ pWl, const float* __restrict__ pbl,
        const float* __restrict__ pWr, const float* __restrict__ pbr,
        float* __restrict__ xl, float* __restrict__ xr) {
    __shared__ float xs[32 * EMB];       // 32 KB
    __shared__ float Bs[2][16 * 256];    // 2 x 16 KB: cols 0-127 Wl, 128-255 Wr
    __shared__ int   ctl[32];
    __shared__ float ldl[32];
    const int t  = threadIdx.x;
    const int n0 = blockIdx.x * 32;

    if (t < 32) {
        int n = n0 + t; if (n >= N) n = N - 1;
        ctl[t] = ct[n];
        ldl[t] = ldsc[n];
    }
    __syncthreads();

    // stage B chunk 0 (independent of xs)
    #pragma unroll
    for (int j = 0; j < 4; j++) {
        int fi  = t + j * 256;
        int kk  = fi >> 6;
        int col = (fi & 63) * 4;
        const float* src = (col < HID) ? (pWl + (size_t)kk * HID + col)
                                       : (pWr + (size_t)kk * HID + col - HID);
        *reinterpret_cast<float4*>(&Bs[0][kk * 256 + col]) =
            *reinterpret_cast<const float4*>(src);
    }
    // stage xs = elu(embed), 8 float4 per thread (64 lanes per row -> coalesced)
    #pragma unroll
    for (int j = 0; j < 8; j++) {
        int fi  = t + j * 256;
        int row = fi >> 6;
        int col = (fi & 63) * 4;
        float l = ldl[row];
        float4 wc  = *reinterpret_cast<const float4*>(We + (size_t)ctl[row] * EMB + col);
        float4 w32 = *reinterpret_cast<const float4*>(We + (size_t)NCT * EMB + col);
        float4 bb  = *reinterpret_cast<const float4*>(be + col);
        float4 v;
        v.x = fmaf(l, w32.x, wc.x) + bb.x;
        v.y = fmaf(l, w32.y, wc.y) + bb.y;
        v.z = fmaf(l, w32.z, wc.z) + bb.z;
        v.w = fmaf(l, w32.w, wc.w) + bb.w;
        v.x = v.x > 0.f ? v.x : expm1f(v.x);
        v.y = v.y > 0.f ? v.y : expm1f(v.y);
        v.z = v.z > 0.f ? v.z : expm1f(v.z);
        v.w = v.w > 0.f ? v.w : expm1f(v.w);
        *reinterpret_cast<float4*>(&xs[row * EMB + col]) = v;
    }
    __syncthreads();

    const int rg = t >> 6;               // wave-uniform rowgrp: rows rg*8..+7
    const int c  = (t & 63) * 4;         // combined col
    const float* xrow = xs + rg * 8 * EMB;

    float4 acc[8];
    #pragma unroll
    for (int r = 0; r < 8; r++) acc[r] = make_float4(0.f, 0.f, 0.f, 0.f);

    int cur = 0;
    for (int kc = 0; kc < EMB; kc += 16) {
        if (kc + 16 < EMB) {             // prefetch next chunk into other buffer
            #pragma unroll
            for (int j = 0; j < 4; j++) {
                int fi  = t + j * 256;
                int kk  = fi >> 6;
                int col = (fi & 63) * 4;
                const float* src = (col < HID)
                    ? (pWl + (size_t)(kc + 16 + kk) * HID + col)
                    : (pWr + (size_t)(kc + 16 + kk) * HID + col - HID);
                *reinterpret_cast<float4*>(&Bs[cur ^ 1][kk * 256 + col]) =
                    *reinterpret_cast<const float4*>(src);
            }
        }
        #pragma unroll
        for (int kk = 0; kk < 16; kk += 4) {
            float4 a[8];
            #pragma unroll
            for (int r = 0; r < 8; r++)
                a[r] = *reinterpret_cast<const float4*>(xrow + r * EMB + kc + kk);
            #pragma unroll
            for (int q = 0; q < 4; q++) {
                float4 bq = *reinterpret_cast<const float4*>(&Bs[cur][(kk + q) * 256 + c]);
                #pragma unroll
                for (int r = 0; r < 8; r++)
                    acc[r] = fma4s((&a[r].x)[q], bq, acc[r]);
            }
        }
        __syncthreads();
        cur ^= 1;
    }

    float* outP;
    float4 bias;
    int cc;
    if (c < HID) {
        outP = xl; cc = c;
        bias = *reinterpret_cast<const float4*>(pbl + cc);
    } else {
        outP = xr; cc = c - HID;
        bias = *reinterpret_cast<const float4*>(pbr + cc);
    }
    #pragma unroll
    for (int r = 0; r < 8; r++) {
        int n = n0 + rg * 8 + r;
        if (n < N)
            *reinterpret_cast<float4*>(outP + (size_t)n * HID + cc) = add4(acc[r], bias);
    }
}

// ---------------------------------------------------------------------------
// 3-phase exclusive scan of hist[N] -> offs[N+1], cursor copy
// ---------------------------------------------------------------------------
__global__ __launch_bounds__(1024) void k_scan1(const int* __restrict__ hist,
                                                int* __restrict__ offs,
                                                int* __restrict__ bsum) {
    __shared__ int sb[2][1024];
    const int t = threadIdx.x;
    const int i = blockIdx.x * 1024 + t;
    int v = (i < N) ? hist[i] : 0;
    sb[0][t] = v;
    __syncthreads();
    int pin = 0;
    for (int off = 1; off < 1024; off <<= 1) {
        int x = sb[pin][t];
        if (t >= off) x += sb[pin][t - off];
        sb[pin ^ 1][t] = x;
        pin ^= 1;
        __syncthreads();
    }
    int incl = sb[pin][t];
    if (i < N) offs[i] = incl - v;
    if (t == 1023) bsum[blockIdx.x] = incl;
}

__global__ void k_scan2(const int* __restrict__ bsum, int* __restrict__ bbase) {
    if (threadIdx.x == 0) {
        int run = 0;
        for (int j = 0; j < NB_SCAN; j++) { bbase[j] = run; run += bsum[j]; }
    }
}

__global__ __launch_bounds__(1024) void k_scan3(int* __restrict__ offs,
                                                int* __restrict__ cursor,
                                                const int* __restrict__ bbase) {
    const int t = threadIdx.x;
    const int i = blockIdx.x * 1024 + t;
    if (i < N) {
        int v = offs[i] + bbase[blockIdx.x];
        offs[i] = v;
        cursor[i] = v;
    }
    if (blockIdx.x == 0 && t == 0) offs[N] = E;
}

// ---------------------------------------------------------------------------
// k_scatter: CSR adjacency storing SRC node id per slot (grouped by dst)
// ---------------------------------------------------------------------------
__global__ __launch_bounds__(256) void k_scatter(const int* __restrict__ eidx,
                                                 int* __restrict__ cursor,
                                                 int* __restrict__ sorted) {
    const int e = blockIdx.x * 256 + threadIdx.x;
    if (e < E) {
        int s = eidx[e];
        int d = eidx[E + e];
        int pos = atomicAdd(&cursor[d], 1);
        sorted[pos] = s;
    }
}

// ---------------------------------------------------------------------------
// k_agg: fused edge-logit + online scatter-softmax + aggregation.
// 32 lanes per node (float4/lane), 2 nodes per wave, branchless online
// update, 4-deep row prefetch. Writes h over xr (own row only).
// ---------------------------------------------------------------------------
__global__ __launch_bounds__(256, 8) void k_agg(
        const int* __restrict__ offs, const int* __restrict__ srt,
        const float* __restrict__ xl, const float* __restrict__ attv,
        const float* __restrict__ gb, float* xrh) {
    const int t = threadIdx.x;
    const int n = blockIdx.x * 8 + (t >> 5);
    if (n >= N) return;
    const int lane = t & 31;
    const float4* xl4 = reinterpret_cast<const float4*>(xl);
    float4* xh4 = reinterpret_cast<float4*>(xrh);

    const float4 xr4 = xh4[(size_t)n * 32 + lane];
    const float4 at4 = reinterpret_cast<const float4*>(attv)[lane];
    const int i0  = offs[n];
    const int deg = offs[n + 1] - i0;

    float m = -3.0e38f, den = 0.f;
    float4 acc = make_float4(0.f, 0.f, 0.f, 0.f);

#define STEP(XC) {                                                          \
    float vx = XC.x + xr4.x, vy = XC.y + xr4.y,                             \
          vz = XC.z + xr4.z, vw = XC.w + xr4.w;                             \
    vx = fmaxf(vx, 0.f) + 0.2f * fminf(vx, 0.f);                            \
    vy = fmaxf(vy, 0.f) + 0.2f * fminf(vy, 0.f);                            \
    vz = fmaxf(vz, 0.f) + 0.2f * fminf(vz, 0.f);                            \
    vw = fmaxf(vw, 0.f) + 0.2f * fminf(vw, 0.f);                            \
    float p = fmaf(vx, at4.x, fmaf(vy, at4.y, fmaf(vz, at4.z, vw * at4.w)));\
    p += __shfl_xor(p, 16); p += __shfl_xor(p, 8);                          \
    p += __shfl_xor(p, 4);  p += __shfl_xor(p, 2); p += __shfl_xor(p, 1);   \
    float mn = fmaxf(m, p);                                                 \
    float sc = __expf(m - mn);                                              \
    float w  = __expf(p - mn);                                              \
    den   = fmaf(den, sc, w);                                               \
    acc.x = fmaf(acc.x, sc, w * XC.x);                                      \
    acc.y = fmaf(acc.y, sc, w * XC.y);                                      \
    acc.z = fmaf(acc.z, sc, w * XC.z);                                      \
    acc.w = fmaf(acc.w, sc, w * XC.w);                                      \
    m = mn; }

    if (deg > 0) {
        const int lastI = i0 + deg - 1;
        #define LDX(J) xl4[(size_t)srt[min(i0 + (J), lastI)] * 32 + lane]
        float4 x0 = LDX(0), x1 = LDX(1), x2 = LDX(2), x3 = LDX(3);
        int i = 0;
        for (; i + 4 <= deg; i += 4) {
            const int base = i0 + i + 4;
            float4 n0 = xl4[(size_t)srt[min(base + 0, lastI)] * 32 + lane];
            float4 n1 = xl4[(size_t)srt[min(base + 1, lastI)] * 32 + lane];
            float4 n2 = xl4[(size_t)srt[min(base + 2, lastI)] * 32 + lane];
            float4 n3 = xl4[(size_t)srt[min(base + 3, lastI)] * 32 + lane];
            STEP(x0); STEP(x1); STEP(x2); STEP(x3);
            x0 = n0; x1 = n1; x2 = n2; x3 = n3;
        }
        if (i     < deg) STEP(x0);
        if (i + 1 < deg) STEP(x1);
        if (i + 2 < deg) STEP(x2);
        #undef LDX
    }
#undef STEP

    float inv = 1.f / (den + 1e-16f);
    const float4 g4 = reinterpret_cast<const float4*>(gb)[lane];
    float hx = fmaf(acc.x, inv, g4.x);
    float hy = fmaf(acc.y, inv, g4.y);
    float hz = fmaf(acc.z, inv, g4.z);
    float hw = fmaf(acc.w, inv, g4.w);
    hx = hx > 0.f ? hx : expm1f(hx);
    hy = hy > 0.f ? hy : expm1f(hy);
    hz = hz > 0.f ? hz : expm1f(hz);
    hw = hw > 0.f ? hw : expm1f(hw);
    xh4[(size_t)n * 32 + lane] = make_float4(hx, hy, hz, hw);
}

// ---------------------------------------------------------------------------
// k_out v2: block = 32 rows x 512 cols; 256 thr = 4 rowgrp(=wave: perfect
// A broadcast) x 64 colgrp; thread = 8 rows x 8 cols (two col-halves).
// ---------------------------------------------------------------------------
__global__ __launch_bounds__(256, 3) void k_out(
        const float* __restrict__ h, const int* __restrict__ ct,
        const float* __restrict__ Wo, const float* __restrict__ bo,
        const float* __restrict__ spt, float* __restrict__ out) {
    __shared__ float hs[32 * HID];   // 16 KB
    __shared__ float Bs[16 * OUTD];  // 32 KB
    __shared__ int ctl[32];
    const int t  = threadIdx.x;
    const int n0 = blockIdx.x * 32;

    if (t < 32) { int n = n0 + t; ctl[t] = ct[n < N ? n : N - 1]; }
    {
        const float4* h4 = reinterpret_cast<const float4*>(h);
        #pragma unroll
        for (int j = 0; j < 4; j++) {
            int fi  = t + j * 256;           // 0..1023
            int row = fi >> 5;               // 0..31
            int k4  = (fi & 31) * 4;
            int n = n0 + row;
            float4 v = (n < N) ? h4[(size_t)n * 32 + (fi & 31)]
                               : make_float4(0.f, 0.f, 0.f, 0.f);
            *reinterpret_cast<float4*>(&hs[row * HID + k4]) = v;
        }
    }

    const int rg = t >> 6;                   // wave id: rows rg*8..+7
    const int cg = t & 63;
    const int c0 = cg * 4;                   // col-half 0
    const int c1 = 256 + cg * 4;             // col-half 1
    const float* hrow = hs + rg * 8 * HID;
    const int st_kk  = t >> 7;
    const int st_col = (t & 127) * 4;

    float4 acc0[8], acc1[8];
    #pragma unroll
    for (int r = 0; r < 8; r++) {
        acc0[r] = make_float4(0.f, 0.f, 0.f, 0.f);
        acc1[r] = make_float4(0.f, 0.f, 0.f, 0.f);
    }

    for (int kc = 0; kc < HID; kc += 16) {
        __syncthreads();                     // hs ready / prev chunk consumed
        #pragma unroll
        for (int j = 0; j < 8; j++) {
            int kk = st_kk + j * 2;
            *reinterpret_cast<float4*>(&Bs[kk * OUTD + st_col]) =
                *reinterpret_cast<const float4*>(Wo + (size_t)(kc + kk) * OUTD + st_col);
        }
        __syncthreads();

        #pragma unroll
        for (int kk = 0; kk < 16; kk += 4) {
            float4 a[8];
            #pragma unroll
            for (int r = 0; r < 8; r++)
                a[r] = *reinterpret_cast<const float4*>(hrow + r * HID + kc + kk);
            #pragma unroll
            for (int q = 0; q < 4; q++) {
                float4 b0 = *reinterpret_cast<const float4*>(&Bs[(kk + q) * OUTD + c0]);
                float4 b1 = *reinterpret_cast<const float4*>(&Bs[(kk + q) * OUTD + c1]);
                const float* aq = reinterpret_cast<const float*>(a);
                #pragma unroll
                for (int r = 0; r < 8; r++) {
                    float av = aq[r * 4 + q];
                    acc0[r] = fma4s(av, b0, acc0[r]);
                    acc1[r] = fma4s(av, b1, acc1[r]);
                }
            }
        }
    }

    float* outd = out + (size_t)N * OUTD;
    const float4 bias0 = *reinterpret_cast<const float4*>(bo + c0);
    const float4 bias1 = *reinterpret_cast<const float4*>(bo + c1);
    #pragma unroll
    for (int r = 0; r < 8; r++) {
        int row = rg * 8 + r;
        int n = n0 + row;
        if (n < N) {
            *reinterpret_cast<float4*>(out + (size_t)n * OUTD + c0) = add4(acc0[r], bias0);
            *reinterpret_cast<float4*>(out + (size_t)n * OUTD + c1) = add4(acc1[r], bias1);
            int cn = ctl[row];
            *reinterpret_cast<float4*>(outd + (size_t)n * OUTD + c0) =
                *reinterpret_cast<const float4*>(spt + cn * OUTD + c0);
            *reinterpret_cast<float4*>(outd + (size_t)n * OUTD + c1) =
                *reinterpret_cast<const float4*>(spt + cn * OUTD + c1);
        }
    }
}

// ---------------------------------------------------------------------------
extern "C" void kernel_launch(void* const* d_in, const int* in_sizes, int n_in,
                              void* d_out, int out_size, void* d_ws, size_t ws_size,
                              hipStream_t stream) {
    const float* onehot     = (const float*)d_in[0];
    const float* ldsc       = (const float*)d_in[1];
    const int*   eidx       = (const int*)  d_in[2];
    const float* We         = (const float*)d_in[3];
    const float* be         = (const float*)d_in[4];
    const float* Wl         = (const float*)d_in[5];
    const float* bl         = (const float*)d_in[6];
    const float* Wr         = (const float*)d_in[7];
    const float* br         = (const float*)d_in[8];
    const float* attv       = (const float*)d_in[9];
    const float* gb         = (const float*)d_in[10];
    const float* Wo         = (const float*)d_in[11];
    const float* bo         = (const float*)d_in[12];
    const float* dispersion = (const float*)d_in[13];

    float* ws     = (float*)d_ws;
    float* xl     = ws;                               // N*HID
    float* xr     = xl + (size_t)N * HID;             // N*HID (h after k_agg)
    int*   sorted = (int*)(xr + (size_t)N * HID);     // E (src ids by dst)
    int*   ct     = sorted + E;                       // N
    int*   offs   = ct + N;                           // N+1
    int*   cursor = offs + (N + 1);                   // N+1
    int*   hist   = cursor + (N + 1);                 // N
    float* spt    = (float*)(hist + N);               // NCT*OUTD
    int*   bsum   = (int*)(spt + NCT * OUTD);         // 64
    int*   bbase  = bsum + 64;                        // 64

    float* out = (float*)d_out;

    k_init   <<<(N + 255) / 256, 256, 0, stream>>>(onehot, dispersion, ct, hist, spt);
    k_hist   <<<(E / 4 + 255) / 256, 256, 0, stream>>>(eidx, hist);
    k_xlr    <<<(N + 31) / 32, 256, 0, stream>>>(ct, ldsc, We, be, Wl, bl, Wr, br, xl, xr);
    k_scan1  <<<NB_SCAN, 1024, 0, stream>>>(hist, offs, bsum);
    k_scan2  <<<1, 64, 0, stream>>>(bsum, bbase);
    k_scan3  <<<NB_SCAN, 1024, 0, stream>>>(offs, cursor, bbase);
    k_scatter<<<(E + 255) / 256, 256, 0, stream>>>(eidx, cursor, sorted);
    k_agg    <<<(N + 7) / 8, 256, 0, stream>>>(offs, sorted, xl, attv, gb, xr);
    k_out    <<<(N + 31) / 32, 256, 0, stream>>>(xr, ct, Wo, bo, spt, out);
}